// Round 11
// baseline (295.540 us; speedup 1.0000x reference)
//
#include <hip/hip_runtime.h>
#include <hip/hip_bf16.h>
#include <hip/hip_fp16.h>
#include <math.h>

#define D    1024
#define H    16
#define DH   64
#define S    1024
#define M    1024
#define B    2
#define J    2048          // M + S
#define SCALE 0.125f       // 1/sqrt(64)

typedef __attribute__((ext_vector_type(8))) short        bf16x8;
typedef __attribute__((ext_vector_type(4))) short        s16x4;
typedef __attribute__((ext_vector_type(8))) _Float16     h16x8;
typedef __attribute__((ext_vector_type(8))) unsigned short us8;
typedef __attribute__((ext_vector_type(4))) float        f32x4;

__device__ __forceinline__ short f2bs(float f) {
    __hip_bfloat16 t = __float2bfloat16(f);
    short r; __builtin_memcpy(&r, &t, 2); return r;
}
// fast bf16 pack (round-half-up); inputs finite non-negative (probs)
__device__ __forceinline__ unsigned short f2bf_fast(float f) {
    unsigned int u; __builtin_memcpy(&u, &f, 4);
    return (unsigned short)((u + 0x8000u) >> 16);
}

// async global->LDS, 16 bytes per lane
__device__ __forceinline__ void g2l16(const short* g, short* l) {
    __builtin_amdgcn_global_load_lds(
        (const __attribute__((address_space(1))) unsigned int*)g,
        (__attribute__((address_space(3))) unsigned int*)l, 16, 0, 0);
}

// ---------------------------------------------------------------------------
// prep: blocks [0,6144)  fp32->bf16 flat convert (mem||x -> a_bf, pemb -> p_bf)
//       blocks [6144,7424) 64x64 weight transpose+convert W[k][n] -> Wt[n][k]
// ---------------------------------------------------------------------------
__global__ __launch_bounds__(256)
void prep(const float* __restrict__ mem, const float* __restrict__ x,
          const float* __restrict__ pemb,
          const float* __restrict__ Wkv, const float* __restrict__ Wq,
          const float* __restrict__ Wpos, const float* __restrict__ Wout,
          short* __restrict__ a_bf, short* __restrict__ p_bf,
          short* __restrict__ wkvt, short* __restrict__ wqt,
          short* __restrict__ wpt,  short* __restrict__ wot)
{
    __shared__ float t[64][65];
    int blk = blockIdx.x;
    const int tid = threadIdx.x;
    if (blk < 6144) {
        const int idx = (blk * 256 + tid) * 4;
        const int TWO_M = 2 * 1024 * 1024;
        float4 v; short* dst;
        if (idx < TWO_M)          { v = *(const float4*)(mem  + idx);           dst = a_bf + idx; }
        else if (idx < 2 * TWO_M) { v = *(const float4*)(x    + idx - TWO_M);   dst = a_bf + idx; }
        else                      { v = *(const float4*)(pemb + idx - 2*TWO_M); dst = p_bf + idx - 2*TWO_M; }
        s16x4 o = { f2bs(v.x), f2bs(v.y), f2bs(v.z), f2bs(v.w) };
        *(s16x4*)dst = o;
        return;
    }
    blk -= 6144;
    const float* src; short* dst; int N, t0;
    if (blk < 512)       { src = Wkv;  dst = wkvt; N = 2048; t0 = blk; }
    else if (blk < 768)  { src = Wq;   dst = wqt;  N = 1024; t0 = blk - 512; }
    else if (blk < 1024) { src = Wpos; dst = wpt;  N = 1024; t0 = blk - 768; }
    else                 { src = Wout; dst = wot;  N = 1024; t0 = blk - 1024; }
    const int ntn = N >> 6;
    const int k0 = (t0 / ntn) * 64, n0 = (t0 % ntn) * 64;
    #pragma unroll
    for (int e = tid; e < 4096; e += 256) {
        int r = e >> 6, c = e & 63;
        t[r][c] = src[(size_t)(k0 + r) * N + n0 + c];
    }
    __syncthreads();
    #pragma unroll
    for (int e = tid; e < 4096; e += 256) {
        int nr = e >> 6, kc = e & 63;
        dst[(size_t)(n0 + nr) * 1024 + k0 + kc] = f2bs(t[kc][nr]);
    }
}

// ---------------------------------------------------------------------------
// Shared MFMA GEMM core: BM=BN=128, BK=64, 256 thr, K=1024.
// ---------------------------------------------------------------------------
__device__ __forceinline__ void gemm_core(const short* __restrict__ A,
                                          const short* __restrict__ Bt,
                                          short* As, short* Bs,
                                          int bm0, int bn0, int tid,
                                          f32x4 acc[4][4])
{
    const int w    = tid >> 6;
    const int wy   = w >> 1, wx = w & 1;
    const int lane = tid & 63;
    const int lm   = lane & 15;
    const int lq   = lane >> 4;

    for (int k0 = 0; k0 < 1024; k0 += 64) {
        const short* Ab = A  + (size_t)bm0 * 1024 + k0;
        const short* Bb = Bt + (size_t)bn0 * 1024 + k0;
        #pragma unroll
        for (int t = 0; t < 4; ++t) {
            int s = t * 256 + tid;
            int r = s >> 3, c = s & 7;
            int cg = c ^ (r & 7);
            g2l16(Ab + r * 1024 + cg * 8, As + s * 8);
            g2l16(Bb + r * 1024 + cg * 8, Bs + s * 8);
        }
        __syncthreads();
        #pragma unroll
        for (int kk = 0; kk < 2; ++kk) {
            bf16x8 af[4], bg[4];
            #pragma unroll
            for (int r4 = 0; r4 < 4; ++r4) {
                int ar = wy * 64 + r4 * 16 + lm;
                int kc = kk * 4 + lq;
                af[r4] = *(const bf16x8*)(As + ((ar << 3) + (kc ^ (ar & 7))) * 8);
            }
            #pragma unroll
            for (int c4 = 0; c4 < 4; ++c4) {
                int br = wx * 64 + c4 * 16 + lm;
                int kc = kk * 4 + lq;
                bg[c4] = *(const bf16x8*)(Bs + ((br << 3) + (kc ^ (br & 7))) * 8);
            }
            #pragma unroll
            for (int r4 = 0; r4 < 4; ++r4)
                #pragma unroll
                for (int c4 = 0; c4 < 4; ++c4)
                    acc[r4][c4] = __builtin_amdgcn_mfma_f32_16x16x32_bf16(
                        af[r4], bg[c4], acc[r4][c4], 0, 0, 0);
        }
        __syncthreads();
    }
}

// ---------------------------------------------------------------------------
// Fused kv/q/r projections (unchanged).
// ---------------------------------------------------------------------------
__global__ __launch_bounds__(256)
void proj_fused(const short* __restrict__ a_bf, const short* __restrict__ p_bf,
                const short* __restrict__ wkvt, const short* __restrict__ wqt,
                const short* __restrict__ wpt,
                short* __restrict__ k_bf, short* __restrict__ vt_bf,
                short* __restrict__ qu_bf, short* __restrict__ qv_bf,
                short* __restrict__ r_bf,
                const float* __restrict__ uvec, const float* __restrict__ vvec)
{
    __shared__ __align__(16) short As[128 * 64];
    __shared__ __align__(16) short Bs[128 * 64];

    int blk = blockIdx.x;
    int mode, bx, by;
    const short *A, *Bt;
    if (blk < 512)      { bx = blk & 15; by = blk >> 4;
                          if (bx >= 8) { mode = 4; A = wkvt; Bt = a_bf; }   // swapped V
                          else         { mode = 0; A = a_bf; Bt = wkvt; } }
    else if (blk < 640) { int b2 = blk - 512; mode = 1; bx = b2 & 7; by = b2 >> 3;
                          A = a_bf + (size_t)2048 * 1024; Bt = wqt; }
    else                { int b3 = blk - 640; mode = 2; bx = b3 & 7; by = b3 >> 3;
                          A = p_bf; Bt = wpt; }
    const int bn0 = (mode == 4) ? by * 128 : bx * 128;
    const int bm0 = (mode == 4) ? bx * 128 : by * 128;
    const int tid = threadIdx.x;
    const int w = tid >> 6, wy = w >> 1, wx = w & 1;
    const int lane = tid & 63, lm = lane & 15, lq = lane >> 4;

    f32x4 acc[4][4];
    #pragma unroll
    for (int r = 0; r < 4; ++r)
        #pragma unroll
        for (int c = 0; c < 4; ++c) acc[r][c] = (f32x4){0.f, 0.f, 0.f, 0.f};

    gemm_core(A, Bt, As, Bs, bm0, bn0, tid, acc);

    #pragma unroll
    for (int r4 = 0; r4 < 4; ++r4) {
        #pragma unroll
        for (int c4 = 0; c4 < 4; ++c4) {
            const int n = bn0 + wx * 64 + c4 * 16 + lm;
            float ubias = 0.f, vbias = 0.f;
            if (mode == 1) { ubias = uvec[n]; vbias = vvec[n]; }
            #pragma unroll
            for (int reg = 0; reg < 4; ++reg) {
                const int m = bm0 + wy * 64 + r4 * 16 + lq * 4 + reg;
                const float val = acc[r4][c4][reg];
                if (mode == 0) {
                    int j = m >> 1, b = m & 1;
                    int h = n >> 6, d = n & 63;
                    k_bf[(((size_t)b * H + h) * J + j) * DH + d] = f2bs(val);
                } else if (mode == 4) {
                    int n2 = m - 1024, h = n2 >> 6, d = n2 & 63;
                    int j = n >> 1, b = n & 1;
                    vt_bf[(((size_t)b * H + h) * DH + d) * J + j] = f2bs(val);
                } else if (mode == 1) {
                    int i = m >> 1, b = m & 1;
                    int h = n >> 6, d = n & 63;
                    size_t o = (((size_t)b * H + h) * S + i) * DH + d;
                    qu_bf[o] = f2bs((val + ubias) * SCALE);
                    qv_bf[o] = f2bs((val + vbias) * SCALE);
                } else {
                    int h = n >> 6, d = n & 63;
                    r_bf[((size_t)h * J + m) * DH + d] = f2bs(val);
                }
            }
        }
    }
}

// ---------------------------------------------------------------------------
// Output projection: M=2048, N=1024, fp32 out.
// ---------------------------------------------------------------------------
__global__ __launch_bounds__(256)
void gemm_out(const short* __restrict__ A, const short* __restrict__ Bt,
              float* __restrict__ out)
{
    __shared__ __align__(16) short As[128 * 64];
    __shared__ __align__(16) short Bs[128 * 64];
    const int bn0 = blockIdx.x * 128, bm0 = blockIdx.y * 128;
    const int tid = threadIdx.x;
    const int w = tid >> 6, wy = w >> 1, wx = w & 1;
    const int lane = tid & 63, lm = lane & 15, lq = lane >> 4;

    f32x4 acc[4][4];
    #pragma unroll
    for (int r = 0; r < 4; ++r)
        #pragma unroll
        for (int c = 0; c < 4; ++c) acc[r][c] = (f32x4){0.f, 0.f, 0.f, 0.f};

    gemm_core(A, Bt, As, Bs, bm0, bn0, tid, acc);

    #pragma unroll
    for (int r4 = 0; r4 < 4; ++r4)
        #pragma unroll
        for (int c4 = 0; c4 < 4; ++c4) {
            const int n = bn0 + wx * 64 + c4 * 16 + lm;
            #pragma unroll
            for (int reg = 0; reg < 4; ++reg) {
                const int m = bm0 + wy * 64 + r4 * 16 + lq * 4 + reg;
                out[(size_t)m * 1024 + n] = acc[r4][c4][reg];
            }
        }
}

// ---------------------------------------------------------------------------
// MFMA attention: block = 32 query rows x one (b,h) x one j-half (1024 cols).
// 512 thr, 64 KB LDS. R10: softmax LDS pass ELIMINATED — PV waves own a
// j-eighth x all 64 d; A-frags (raw fp16 logits) read once, exp'd in-register
// (no max-sub, per R9), packed to bf16, row-sums shuffle-reduced and written
// straight to global lsum. 8 per-wave O-partials in scF (64 KB exactly),
// float4 epilogue sum. Pos/content phases unchanged from R9.
// ---------------------------------------------------------------------------
__device__ __forceinline__ int sidx(int m, int c) {   // m in [0,32), c in [0,1024)
    return (m << 10) + (c ^ (m << 3));
}

__global__ __launch_bounds__(512)
void attn_mfma(const short* __restrict__ qu_bf, const short* __restrict__ qv_bf,
               const short* __restrict__ k_bf,  const short* __restrict__ vt_bf,
               const short* __restrict__ r_bf,
               float* __restrict__ opart, float* __restrict__ lsum)
{
    __shared__ __align__(16) unsigned short sc[32 * 1024];   // 64 KB
    __half* sch = (__half*)sc;
    float*  scF = (float*)sc;                  // reused after PV reads

    const int bh  = blockIdx.x;                // fastest: 32 independent streams
    const int it  = blockIdx.y;
    const int jh  = blockIdx.z;
    const int i0  = it * 32;
    const int cbeg = jh << 10, cend = cbeg + 1024;
    const int h   = bh & (H - 1);
    const int tid = threadIdx.x;
    const int w    = tid >> 6;       // 0..7
    const int lane = tid & 63;
    const int lm   = lane & 15;
    const int lq   = lane >> 4;
    const int slot = (it * 32 + bh) * 2 + jh;

    // ---- A fragments ----
    const short* qup0 = qu_bf + ((size_t)(bh * S + i0 + lm)) * DH + lq * 8;
    const short* qup1 = qup0 + 16 * DH;
    bf16x8 au00 = *(const bf16x8*)qup0,        au01 = *(const bf16x8*)(qup0 + 32);
    bf16x8 au10 = *(const bf16x8*)qup1,        au11 = *(const bf16x8*)(qup1 + 32);
    const short* qvp0 = qv_bf + ((size_t)(bh * S + i0 + lm)) * DH + lq * 8;
    const short* qvp1 = qvp0 + 16 * DH;
    bf16x8 av00 = *(const bf16x8*)qvp0,        av01 = *(const bf16x8*)(qvp0 + 32);
    bf16x8 av10 = *(const bf16x8*)qvp1,        av11 = *(const bf16x8*)(qvp1 + 32);
    int r1a = i0 + 1 + lm;  if (r1a > S - 1) r1a = S - 1;   // clamped rows masked
    int r1b = i0 + 17 + lm; if (r1b > S - 1) r1b = S - 1;
    const short* qwp0 = qv_bf + ((size_t)(bh * S + r1a)) * DH + lq * 8;
    const short* qwp1 = qv_bf + ((size_t)(bh * S + r1b)) * DH + lq * 8;
    bf16x8 aw00 = *(const bf16x8*)qwp0,        aw01 = *(const bf16x8*)(qwp0 + 32);
    bf16x8 aw10 = *(const bf16x8*)qwp1,        aw11 = *(const bf16x8*)(qwp1 + 32);

    // ---- zero the pos hole column: row m, col i0+m+1025 (if in window) ----
    if (tid < 32) {
        int hole = i0 + tid + 1025;
        if (hole >= cbeg && hole < cend) sc[sidx(tid, hole - cbeg)] = 0;
    }

    const short* rbase = r_bf + (size_t)h * J * DH;

    // ---- pos main: col = i0 + 16t + lm + m - 1023; interior/edge split ----
    {
        int tmp = cbeg + 977 - i0;
        int tlo = tmp > 0 ? ((tmp + 15) >> 4) : 0;
        int thi = (cend + 1022 - i0) >> 4; if (thi > 127) thi = 127;
        for (int t = tlo + w; t <= thi; t += 8) {
            const short* rp = rbase + (size_t)(t * 16 + lm) * DH + lq * 8;
            bf16x8 b0 = *(const bf16x8*)rp, b1 = *(const bf16x8*)(rp + 32);
            f32x4 c0 = {0.f,0.f,0.f,0.f}, c1 = {0.f,0.f,0.f,0.f};
            c0 = __builtin_amdgcn_mfma_f32_16x16x32_bf16(av00, b0, c0, 0, 0, 0);
            c1 = __builtin_amdgcn_mfma_f32_16x16x32_bf16(av10, b0, c1, 0, 0, 0);
            c0 = __builtin_amdgcn_mfma_f32_16x16x32_bf16(av01, b1, c0, 0, 0, 0);
            c1 = __builtin_amdgcn_mfma_f32_16x16x32_bf16(av11, b1, c1, 0, 0, 0);
            int cb = i0 + t * 16 + lm - 1023 - cbeg;     // local col for m=0
            int base = i0 + 16 * t - 1023;               // scalar col_min
            if (base >= cbeg && base + 46 < cend) {
                #pragma unroll
                for (int r = 0; r < 4; ++r) {
                    int m0 = lq * 4 + r, m1 = m0 + 16;
                    sch[sidx(m0, cb + m0)] = __float2half(c0[r]);
                    sch[sidx(m1, cb + m1)] = __float2half(c1[r]);
                }
            } else {
                #pragma unroll
                for (int r = 0; r < 4; ++r) {
                    int m0 = lq * 4 + r, m1 = m0 + 16;
                    int cA = cb + m0, cB = cb + m1;
                    if (cA >= 0 && cA < 1024) sch[sidx(m0, cA)] = __float2half(c0[r]);
                    if (cB >= 0 && cB < 1024) sch[sidx(m1, cB)] = __float2half(c1[r]);
                }
            }
        }
    }

    // ---- pos wrap: col = i0 + 16t + lm + m + 1026, rows Qv[i+1]; split ----
    {
        int tmpw = cbeg - 1072 - i0;
        int tlw = tmpw > 0 ? ((tmpw + 15) >> 4) : 0;
        int thw = (cend - 1027 - i0) >> 4; if (thw > 127) thw = 127;
        for (int t = tlw + w; t <= thw; t += 8) {
            const short* rp = rbase + (size_t)(t * 16 + lm) * DH + lq * 8;
            bf16x8 b0 = *(const bf16x8*)rp, b1 = *(const bf16x8*)(rp + 32);
            f32x4 c0 = {0.f,0.f,0.f,0.f}, c1 = {0.f,0.f,0.f,0.f};
            c0 = __builtin_amdgcn_mfma_f32_16x16x32_bf16(aw00, b0, c0, 0, 0, 0);
            c1 = __builtin_amdgcn_mfma_f32_16x16x32_bf16(aw10, b0, c1, 0, 0, 0);
            c0 = __builtin_amdgcn_mfma_f32_16x16x32_bf16(aw01, b1, c0, 0, 0, 0);
            c1 = __builtin_amdgcn_mfma_f32_16x16x32_bf16(aw11, b1, c1, 0, 0, 0);
            int cb = i0 + t * 16 + lm + 1026 - cbeg;
            int base = i0 + 16 * t + 1026;
            if (base >= cbeg && base + 46 < cend) {
                #pragma unroll
                for (int r = 0; r < 4; ++r) {
                    int m0 = lq * 4 + r, m1 = m0 + 16;
                    sch[sidx(m0, cb + m0)] = __float2half(c0[r]);
                    sch[sidx(m1, cb + m1)] = __float2half(c1[r]);
                }
            } else {
                #pragma unroll
                for (int r = 0; r < 4; ++r) {
                    int m0 = lq * 4 + r, m1 = m0 + 16;
                    int cA = cb + m0, cB = cb + m1;
                    if (cA >= 0 && cA < 1024) sch[sidx(m0, cA)] = __float2half(c0[r]);
                    if (cB >= 0 && cB < 1024) sch[sidx(m1, cB)] = __float2half(c1[r]);
                }
            }
        }
    }

    // ---- prefetch first content K-pair before the barrier ----
    const short* kbase = k_bf + (size_t)bh * J * DH;
    int tc0 = jh * 64 + w + 8 * ((it) & 7);
    int tc1 = jh * 64 + w + 8 * ((1 + it) & 7);
    const short* kp0 = kbase + (size_t)(tc0 * 16 + lm) * DH + lq * 8;
    const short* kp1 = kbase + (size_t)(tc1 * 16 + lm) * DH + lq * 8;
    bf16x8 kb0 = *(const bf16x8*)kp0, kb1 = *(const bf16x8*)(kp0 + 32);
    bf16x8 kb2 = *(const bf16x8*)kp1, kb3 = *(const bf16x8*)(kp1 + 32);
    __syncthreads();

    // ---- content: rolling 2-tile pipeline; acc init from pos values ----
    #pragma unroll 1
    for (int g = 0; g < 8; g += 2) {
        int t0 = jh * 64 + w + 8 * ((g + it) & 7);
        int t1 = jh * 64 + w + 8 * ((g + 1 + it) & 7);
        bf16x8 nb0, nb1, nb2, nb3;
        if (g + 2 < 8) {
            int u0 = jh * 64 + w + 8 * ((g + 2 + it) & 7);
            int u1 = jh * 64 + w + 8 * ((g + 3 + it) & 7);
            const short* np0 = kbase + (size_t)(u0 * 16 + lm) * DH + lq * 8;
            const short* np1 = kbase + (size_t)(u1 * 16 + lm) * DH + lq * 8;
            nb0 = *(const bf16x8*)np0; nb1 = *(const bf16x8*)(np0 + 32);
            nb2 = *(const bf16x8*)np1; nb3 = *(const bf16x8*)(np1 + 32);
        }
        int lc0 = t0 * 16 + lm - cbeg;
        int lc1 = t1 * 16 + lm - cbeg;
        f32x4 c0, c1, c2, c3;
        #pragma unroll
        for (int r = 0; r < 4; ++r) {
            c0[r] = __half2float(sch[sidx(lq * 4 + r, lc0)]);
            c1[r] = __half2float(sch[sidx(16 + lq * 4 + r, lc0)]);
            c2[r] = __half2float(sch[sidx(lq * 4 + r, lc1)]);
            c3[r] = __half2float(sch[sidx(16 + lq * 4 + r, lc1)]);
        }
        c0 = __builtin_amdgcn_mfma_f32_16x16x32_bf16(au00, kb0, c0, 0, 0, 0);
        c1 = __builtin_amdgcn_mfma_f32_16x16x32_bf16(au10, kb0, c1, 0, 0, 0);
        c2 = __builtin_amdgcn_mfma_f32_16x16x32_bf16(au00, kb2, c2, 0, 0, 0);
        c3 = __builtin_amdgcn_mfma_f32_16x16x32_bf16(au10, kb2, c3, 0, 0, 0);
        c0 = __builtin_amdgcn_mfma_f32_16x16x32_bf16(au01, kb1, c0, 0, 0, 0);
        c1 = __builtin_amdgcn_mfma_f32_16x16x32_bf16(au11, kb1, c1, 0, 0, 0);
        c2 = __builtin_amdgcn_mfma_f32_16x16x32_bf16(au01, kb3, c2, 0, 0, 0);
        c3 = __builtin_amdgcn_mfma_f32_16x16x32_bf16(au11, kb3, c3, 0, 0, 0);
        #pragma unroll
        for (int r = 0; r < 4; ++r) {
            sch[sidx(lq * 4 + r, lc0)]      = __float2half(c0[r]);
            sch[sidx(16 + lq * 4 + r, lc0)] = __float2half(c1[r]);
            sch[sidx(lq * 4 + r, lc1)]      = __float2half(c2[r]);
            sch[sidx(16 + lq * 4 + r, lc1)] = __float2half(c3[r]);
        }
        kb0 = nb0; kb1 = nb1; kb2 = nb2; kb3 = nb3;
    }
    __syncthreads();

    // ---- PV: wave w -> j-eighth [w*128,(w+1)*128) x ALL 64 d; exp inline ----
    f32x4 acc[4][2];
    #pragma unroll
    for (int ds = 0; ds < 4; ++ds) {
        acc[ds][0] = (f32x4){0.f, 0.f, 0.f, 0.f};
        acc[ds][1] = (f32x4){0.f, 0.f, 0.f, 0.f};
    }
    float rs0 = 0.f, rs1 = 0.f;
    #pragma unroll 1
    for (int c = 0; c < 4; ++c) {
        int jb = w * 128 + ((c + it) & 3) * 32;
        h16x8 ra0 = *(const h16x8*)(sc + sidx(lm, jb + lq * 8));
        h16x8 ra1 = *(const h16x8*)(sc + sidx(16 + lm, jb + lq * 8));
        bf16x8 bv[4];
        #pragma unroll
        for (int ds = 0; ds < 4; ++ds)
            bv[ds] = *(const bf16x8*)(vt_bf +
                ((size_t)bh * DH + ds * 16 + lm) * J + cbeg + jb + lq * 8);
        us8 pa, pb;
        #pragma unroll
        for (int k = 0; k < 8; ++k) {
            float e0 = __builtin_amdgcn_exp2f((float)ra0[k] * 1.44269504f);
            float e1 = __builtin_amdgcn_exp2f((float)ra1[k] * 1.44269504f);
            rs0 += e0; rs1 += e1;
            pa[k] = f2bf_fast(e0);
            pb[k] = f2bf_fast(e1);
        }
        bf16x8 a0, a1;
        __builtin_memcpy(&a0, &pa, 16);
        __builtin_memcpy(&a1, &pb, 16);
        #pragma unroll
        for (int ds = 0; ds < 4; ++ds) {
            acc[ds][0] = __builtin_amdgcn_mfma_f32_16x16x32_bf16(a0, bv[ds], acc[ds][0], 0, 0, 0);
            acc[ds][1] = __builtin_amdgcn_mfma_f32_16x16x32_bf16(a1, bv[ds], acc[ds][1], 0, 0, 0);
        }
    }
    // row sums for this wave's j-eighth: reduce across lq (lane stride 16)
    rs0 += __shfl_xor(rs0, 16); rs0 += __shfl_xor(rs0, 32);
    rs1 += __shfl_xor(rs1, 16); rs1 += __shfl_xor(rs1, 32);
    if (lq == 0) {
        lsum[(size_t)slot * 256 + w * 32 + lm]      = rs0;
        lsum[(size_t)slot * 256 + w * 32 + 16 + lm] = rs1;
    }
    __syncthreads();   // all logit reads retired; sc becomes fp32 regions

    #pragma unroll
    for (int ds = 0; ds < 4; ++ds)
        #pragma unroll
        for (int r = 0; r < 4; ++r) {
            int m0 = lq * 4 + r, m1 = m0 + 16;
            scF[w * 2048 + m0 * 64 + ds * 16 + lm] = acc[ds][0][r];
            scF[w * 2048 + m1 * 64 + ds * 16 + lm] = acc[ds][1][r];
        }
    __syncthreads();

    {
        float* op = opart + (size_t)slot * 2048;
        const int e = tid * 4;
        float4 s = *(const float4*)(scF + e);
        #pragma unroll
        for (int r = 1; r < 8; ++r) {
            float4 t = *(const float4*)(scF + r * 2048 + e);
            s.x += t.x; s.y += t.y; s.z += t.z; s.w += t.w;
        }
        *(float4*)(op + e) = s;
    }
}

// ---------------------------------------------------------------------------
// Merge the two j-half partials: O = (O0 + O1) / (l0 + l1)   (m == 0 both)
// ---------------------------------------------------------------------------
__global__ __launch_bounds__(256)
void attn_combine(const float* __restrict__ opart, const float* __restrict__ lsum,
                  short* __restrict__ o_bf)
{
    const int blk = blockIdx.x;           // it*32 + bh
    const int it = blk >> 5, bh = blk & 31;
    const int h = bh & 15, b = bh >> 4;
    __shared__ float wgt[32];
    const int tid = threadIdx.x;
    if (tid < 32) {
        float l = 0.f;
        #pragma unroll
        for (int wv = 0; wv < 8; ++wv)
            l += lsum[(size_t)(blk * 2 + 0) * 256 + wv * 32 + tid]
               + lsum[(size_t)(blk * 2 + 1) * 256 + wv * 32 + tid];
        wgt[tid] = 1.0f / l;
    }
    __syncthreads();
    const float* p0 = opart + (size_t)(blk * 2 + 0) * 2048;
    const float* p1 = opart + (size_t)(blk * 2 + 1) * 2048;
    #pragma unroll
    for (int e = tid; e < 2048; e += 256) {
        int m = e >> 6, d = e & 63;
        float val = (p0[e] + p1[e]) * wgt[m];
        o_bf[((size_t)(it * 32 + m) * B + b) * (H * DH) + h * DH + d] = f2bs(val);
    }
}

// ---------------------------------------------------------------------------
extern "C" void kernel_launch(void* const* d_in, const int* in_sizes, int n_in,
                              void* d_out, int out_size, void* d_ws, size_t ws_size,
                              hipStream_t stream)
{
    const float* x    = (const float*)d_in[0];   // [S, B, D]
    const float* pemb = (const float*)d_in[1];   // [S+M, D]
    const float* mem  = (const float*)d_in[2];   // [M, B, D]
    const float* u    = (const float*)d_in[3];   // [H, DH]
    const float* v    = (const float*)d_in[4];   // [H, DH]
    const float* Wkv  = (const float*)d_in[5];   // [D, 2*H*DH]
    const float* Wq   = (const float*)d_in[6];   // [D, H*DH]
    const float* Wpos = (const float*)d_in[7];   // [D, H*DH]
    const float* Wout = (const float*)d_in[8];   // [H*DH, D]
    float* out = (float*)d_out;                  // [S, B, D]

    char* p = (char*)d_ws;
    short* a_bf  = (short*)p; p += (size_t)4096 * 1024 * 2;    // mem||x  [0,8M)
    short* p_bf  = (short*)p; p += (size_t)2048 * 1024 * 2;    // [8M,12M)
    short* wkvt  = (short*)p; p += (size_t)2048 * 1024 * 2;    // [12M,16M)
    short* wqt   = (short*)p; p += (size_t)1024 * 1024 * 2;    // [16M,18M)
    short* wpt   = (short*)p; p += (size_t)1024 * 1024 * 2;    // [18M,20M)
    short* wot   = (short*)p; p += (size_t)1024 * 1024 * 2;    // [20M,22M)
    short* k_bf  = (short*)p; p += (size_t)B * H * J * DH * 2;
    short* vt_bf = (short*)p; p += (size_t)B * H * J * DH * 2;
    short* qu_bf = (short*)p; p += (size_t)B * H * S * DH * 2;
    short* qv_bf = (short*)p; p += (size_t)B * H * S * DH * 2;
    short* r_bf  = (short*)p; p += (size_t)H * J * DH * 2;
    short* o_bf  = (short*)p;

    // attn partials alias prep buffers (dead after proj_fused):
    // opart: [0,16M) over a_bf/p_bf/wkvt (2048 slots x 2048 fp32 = 16 MB);
    // lsum: [16M,18M) over wqt (2048 slots x 256 fp32 = 2 MB).
    float* opart = (float*)d_ws;
    float* lsum  = (float*)((char*)d_ws + (size_t)16 * 1024 * 1024);

    prep<<<7424, 256, 0, stream>>>(mem, x, pemb, Wkv, Wq, Wpos, Wout,
                                   a_bf, p_bf, wkvt, wqt, wpt, wot);
    proj_fused<<<768, 256, 0, stream>>>(a_bf, p_bf, wkvt, wqt, wpt,
                                        k_bf, vt_bf, qu_bf, qv_bf, r_bf, u, v);
    attn_mfma<<<dim3(B * H, S / 32, 2), 512, 0, stream>>>(
        qu_bf, qv_bf, k_bf, vt_bf, r_bf, opart, lsum);
    attn_combine<<<(S / 32) * B * H, 256, 0, stream>>>(opart, lsum, o_bf);
    gemm_out<<<dim3(8, 16), 256, 0, stream>>>(o_bf, wot, out);
}